// Round 7
// baseline (544.657 us; speedup 1.0000x reference)
//
#include <hip/hip_runtime.h>
#include <type_traits>

#define H_    32
#define HKV_  8
#define HD_   128
#define D_    4096   // H*HD
#define KVD_  1024   // HKV*HD
#define NQKV_ 6144   // D_ + 2*KVD_

typedef __attribute__((ext_vector_type(8))) short s8v;   // 8 x bf16 bits (4 VGPRs)
typedef __attribute__((ext_vector_type(4))) float f4v;

__device__ __forceinline__ float b2f(unsigned short u) {
  union { unsigned int i; float f; } v; v.i = ((unsigned int)u) << 16; return v.f;
}
__device__ __forceinline__ unsigned short f2b(float f) {
  unsigned int u = __float_as_uint(f);
  u += 0x7fffu + ((u >> 16) & 1u);          // round-to-nearest-even
  return (unsigned short)(u >> 16);
}

// async global->LDS, 16B/lane; LDS dest = wave-uniform base, HW adds lane*16
__device__ __forceinline__ void gload16(const unsigned short* g, unsigned short* l) {
  __builtin_amdgcn_global_load_lds((const __attribute__((address_space(1))) void*)g,
                                   (__attribute__((address_space(3))) void*)l, 16, 0, 0);
}

// ---------------------------------------------------------------------------
// fp32 -> bf16 flat convert (8 elems/thread)
// ---------------------------------------------------------------------------
__global__ void cvt_bf16(const float* __restrict__ x, unsigned short* __restrict__ y,
                         int n8)
{
  int i = blockIdx.x * blockDim.x + threadIdx.x;
  if (i >= n8) return;
  const float4* xp = (const float4*)x + (size_t)i * 2;
  float4 a = xp[0], b = xp[1];
  s8v v;
  v[0] = (short)f2b(a.x); v[1] = (short)f2b(a.y);
  v[2] = (short)f2b(a.z); v[3] = (short)f2b(a.w);
  v[4] = (short)f2b(b.x); v[5] = (short)f2b(b.y);
  v[6] = (short)f2b(b.z); v[7] = (short)f2b(b.w);
  *(s8v*)(y + (size_t)i * 8) = v;
}

// ---------------------------------------------------------------------------
// concat bq|bk|bv -> bqkv fp32 [6144]
// ---------------------------------------------------------------------------
__global__ void concat_bias(const float* __restrict__ bq, const float* __restrict__ bk,
                            const float* __restrict__ bv, float* __restrict__ o)
{
  int i = blockIdx.x * blockDim.x + threadIdx.x;   // < 6144
  float v = (i < D_) ? bq[i] : (i < D_ + KVD_) ? bk[i - D_] : bv[i - D_ - KVD_];
  o[i] = v;
}

// ---------------------------------------------------------------------------
// W [K][N] fp32 -> Wt [N][K] bf16, 64x64 LDS-tiled transpose+convert
// ---------------------------------------------------------------------------
__global__ __launch_bounds__(256) void cvt_transpose(
    const float* __restrict__ W, unsigned short* __restrict__ Wt, int K, int N)
{
  __shared__ unsigned short tile[64][72];
  const int k0 = blockIdx.y * 64, n0 = blockIdx.x * 64;
  const int tid = threadIdx.x;
#pragma unroll
  for (int it = 0; it < 4; ++it) {
    int idx = tid + it * 256;
    int r = idx >> 4;
    int c = (idx & 15) << 2;
    float4 w = *(const float4*)(W + (size_t)(k0 + r) * N + n0 + c);
    tile[c + 0][r] = f2b(w.x); tile[c + 1][r] = f2b(w.y);
    tile[c + 2][r] = f2b(w.z); tile[c + 3][r] = f2b(w.w);
  }
  __syncthreads();
#pragma unroll
  for (int it = 0; it < 2; ++it) {
    int idx = tid + it * 256;
    int n = idx >> 3;
    int kk = (idx & 7) << 3;
    *(s8v*)(Wt + (size_t)(n0 + n) * K + k0 + kk) = *(const s8v*)&tile[n][kk];
  }
}

// ---------------------------------------------------------------------------
// bf16 [T][*] column-slice -> transposed [n][T]. Src stride lds_, 64x64 tiles.
// ---------------------------------------------------------------------------
__global__ __launch_bounds__(256) void vtrans(
    const unsigned short* __restrict__ S, int lds_, unsigned short* __restrict__ Dst,
    int T)
{
  __shared__ unsigned short tile[64][72];
  const int v0 = blockIdx.x * 64, t0 = blockIdx.y * 64;
  const int tid = threadIdx.x;
#pragma unroll
  for (int it = 0; it < 2; ++it) {
    int idx = tid + it * 256;           // 0..511
    int tr = idx >> 3;                  // 0..63
    int vc = (idx & 7) << 3;            // 0..56
    s8v val = *(const s8v*)(S + (size_t)(t0 + tr) * lds_ + v0 + vc);
#pragma unroll
    for (int u = 0; u < 8; ++u) tile[vc + u][tr] = (unsigned short)val[u];
  }
  __syncthreads();
#pragma unroll
  for (int it = 0; it < 2; ++it) {
    int idx = tid + it * 256;
    int vr = idx >> 3;
    int tc = (idx & 7) << 3;
    *(s8v*)(Dst + (size_t)(v0 + vr) * T + t0 + tc) = *(const s8v*)&tile[vr][tc];
  }
}

// ---------------------------------------------------------------------------
// 256x256-tile GEMM, 4 waves with 128x128 wave-tile (QKV projection):
//   C[M][N](ldc) bf16 = A[M][K] @ Bt[N][K]^T + bias
// BK=64, 256 threads (2Mx2N waves), 2-deep LDS dbuf (128 KiB), 1 wave/SIMD
// (launch_bounds(256,1): acc[8][8]=256 VGPR + frags fits under 512).
// Rationale: LDS frag bytes/FLOP ~ (WM+WN)/(WM*WN); 128x128 wave-tile cuts
// frag traffic 33% vs 128x64 (192KB -> 128KB per K-tile/CU), flipping the
// kernel from LDS-BW-bound (~4032 cy/K-tile measured) toward the MFMA floor
// (2061 cy). Same sigma-swizzle as gemm_bt4p (all row bases == 0 mod 16).
// Schedule: 2 phases/K-tile; 8-load units {Ak,Bk}(kh); prologue 16 loads +
// vmcnt(8); each phase issues unit(t+1,kh) then vmcnt(8) retires exactly the
// unit the next phase reads; vmcnt(0) tail only.
// Requires M%256==0, N%256==0, K%64==0, K/64>=2.
// ---------------------------------------------------------------------------
__global__ __launch_bounds__(256, 1) void gemm_w128(
    const unsigned short* __restrict__ A, const unsigned short* __restrict__ Bt,
    const float* __restrict__ bias, unsigned short* __restrict__ C,
    int M, int N, int K, int ldc)
{
  __shared__ __align__(16) unsigned short lds[65536];   // 128 KiB

  const int tid  = threadIdx.x;
  const int wave = tid >> 6;          // 0..3
  const int lane = tid & 63;
  const int l16  = lane & 15;
  const int quad = lane >> 4;
  const int wm   = wave >> 1;         // 0..1
  const int wn   = wave & 1;          // 0..1

  // XCD-bijective chunk swizzle
  const int nbx = N >> 8;
  const int nwg = nbx * (M >> 8);
  int bid = blockIdx.x;
  if ((nwg & 7) == 0) bid = (bid & 7) * (nwg >> 3) + (bid >> 3);
  const int row0 = (bid / nbx) << 8;
  const int col0 = (bid % nbx) << 8;

  // staging: wave covers rows wave*64 + u*16 + (lane>>2), u=0..3; source 16B
  // chunk sigma-permuted (lane-constant): chunk = (lane&3) ^ ((lane>>3)&3)
  const int srow = lane >> 2;
  const int scol = (((lane & 3) ^ ((lane >> 3) & 3)) << 3);
  const unsigned short* ApL = A  + (size_t)(row0 + wave * 64 + srow) * K + scol;
  const unsigned short* BpL = Bt + (size_t)(col0 + wave * 64 + srow) * K + scol;

  unsigned short* ldsA = lds;             // buf*16384 + kh*8192 + row*32 + e
  unsigned short* ldsB = lds + 32768;
  const int wst = wave * 2048;            // wave*64 rows * 32 elems

  // frag-read slot addend (lane-constant): quad ^ ((l16>>1)&3)
  const int sl = ((quad ^ ((l16 >> 1) & 3)) << 3);
  const int arow = wm * 128 + l16;        // + i*16
  const int brow = wn * 128 + l16;        // + j*16

  f4v acc[8][8] = {};
  const int nt = K >> 6;

  // prologue: stage tile 0 (units Ak0,Bk0,Ak1,Bk1 = 4 loads each)
  {
#pragma unroll
    for (int u = 0; u < 4; ++u)
      gload16(ApL + (size_t)(u * 16) * K,      ldsA + wst + u * 512);
#pragma unroll
    for (int u = 0; u < 4; ++u)
      gload16(BpL + (size_t)(u * 16) * K,      ldsB + wst + u * 512);
#pragma unroll
    for (int u = 0; u < 4; ++u)
      gload16(ApL + 32 + (size_t)(u * 16) * K, ldsA + 8192 + wst + u * 512);
#pragma unroll
    for (int u = 0; u < 4; ++u)
      gload16(BpL + 32 + (size_t)(u * 16) * K, ldsB + 8192 + wst + u * 512);
  }
  asm volatile("s_waitcnt vmcnt(8)" ::: "memory");   // Ak0(0),Bk0(0) landed
  asm volatile("s_barrier" ::: "memory");

  for (int t = 0; t < nt; ++t) {
    const int p = t & 1;
    const unsigned short* Ab0 = ldsA + p * 16384;      // k-half 0
    const unsigned short* Ab1 = Ab0 + 8192;            // k-half 1
    const unsigned short* Bb0 = ldsB + p * 16384;
    const unsigned short* Bb1 = Bb0 + 8192;
    unsigned short* An = ldsA + (p ^ 1) * 16384;
    unsigned short* Bn = ldsB + (p ^ 1) * 16384;
    const bool pre = (t + 1 < nt);
    const unsigned short* sa = ApL + (size_t)(t + 1) * 64;
    const unsigned short* sb = BpL + (size_t)(t + 1) * 64;

    s8v a[8], b[8];

    // ---------- P0: k-half 0 ----------
#pragma unroll
    for (int i = 0; i < 8; ++i)
      a[i] = *(const s8v*)&Ab0[(arow + i * 16) * 32 + sl];
#pragma unroll
    for (int j = 0; j < 8; ++j)
      b[j] = *(const s8v*)&Bb0[(brow + j * 16) * 32 + sl];
    if (pre) {
#pragma unroll
      for (int u = 0; u < 4; ++u)
        gload16(sa + (size_t)(u * 16) * K, An + wst + u * 512);   // Ak0(t+1)
#pragma unroll
      for (int u = 0; u < 4; ++u)
        gload16(sb + (size_t)(u * 16) * K, Bn + wst + u * 512);   // Bk0(t+1)
    }
    __builtin_amdgcn_s_setprio(1);
#pragma unroll
    for (int i = 0; i < 8; ++i)
#pragma unroll
      for (int j = 0; j < 8; ++j)
        acc[i][j] = __builtin_amdgcn_mfma_f32_16x16x32_bf16(a[i], b[j], acc[i][j], 0, 0, 0);
    __builtin_amdgcn_s_setprio(0);
    if (pre) { asm volatile("s_waitcnt vmcnt(8)" ::: "memory"); }  // Ak1,Bk1(t)
    else     { asm volatile("s_waitcnt vmcnt(0)" ::: "memory"); }
    asm volatile("s_barrier" ::: "memory");

    // ---------- P1: k-half 1 ----------
#pragma unroll
    for (int i = 0; i < 8; ++i)
      a[i] = *(const s8v*)&Ab1[(arow + i * 16) * 32 + sl];
#pragma unroll
    for (int j = 0; j < 8; ++j)
      b[j] = *(const s8v*)&Bb1[(brow + j * 16) * 32 + sl];
    if (pre) {
#pragma unroll
      for (int u = 0; u < 4; ++u)
        gload16(sa + 32 + (size_t)(u * 16) * K, An + 8192 + wst + u * 512);  // Ak1(t+1)
#pragma unroll
      for (int u = 0; u < 4; ++u)
        gload16(sb + 32 + (size_t)(u * 16) * K, Bn + 8192 + wst + u * 512);  // Bk1(t+1)
    }
    __builtin_amdgcn_s_setprio(1);
#pragma unroll
    for (int i = 0; i < 8; ++i)
#pragma unroll
      for (int j = 0; j < 8; ++j)
        acc[i][j] = __builtin_amdgcn_mfma_f32_16x16x32_bf16(a[i], b[j], acc[i][j], 0, 0, 0);
    __builtin_amdgcn_s_setprio(0);
    if (pre) { asm volatile("s_waitcnt vmcnt(8)" ::: "memory"); }  // Ak0,Bk0(t+1)
    asm volatile("s_barrier" ::: "memory");
  }

  // ---- epilogue: bias + bf16 store ----
#pragma unroll
  for (int j = 0; j < 8; ++j) {
    const int col = col0 + wn * 128 + j * 16 + l16;
    const float bc = bias[col];
#pragma unroll
    for (int i = 0; i < 8; ++i) {
      const int rowb = row0 + wm * 128 + i * 16 + quad * 4;
#pragma unroll
      for (int r = 0; r < 4; ++r)
        C[(size_t)(rowb + r) * ldc + col] = f2b(acc[i][j][r] + bc);
    }
  }
}

// ---------------------------------------------------------------------------
// 256x128-tile 2-phase pipelined GEMM (O-proj: full 256-wg coverage at 1/CU):
//   C[M][N] fp32 = A[M][K] @ Bt[N][K]^T + bias
// BK=64, 8 waves (2Mx4N, wave-tile 128x32), 512 threads, 2-deep dbuf,
// LDS 96 KiB (A 64K + B 32K). Same sigma-swizzle as gemm_w128.
// Units per K-tile: Ak (2 loads) + Bk (1 load) per k-half -> 3 loads/phase.
// Ledger: prologue 6 loads + vmcnt(3); P0 issues {Ak0,Bk0}(t+1) then
// vmcnt(3) retires {Ak1,Bk1}(t); P1 issues {Ak1,Bk1}(t+1) then vmcnt(3)
// retires {Ak0,Bk0}(t+1). vmcnt(0) only in tail.
// Requires M%256==0, N%128==0, K%64==0, K/64>=2.
// ---------------------------------------------------------------------------
__global__ __launch_bounds__(512, 1) void gemm_on(
    const unsigned short* __restrict__ A, const unsigned short* __restrict__ Bt,
    const float* __restrict__ bias, float* __restrict__ C,
    int M, int N, int K)
{
  __shared__ __align__(16) unsigned short lds[49152];   // 96 KiB

  const int tid  = threadIdx.x;
  const int wave = tid >> 6;          // 0..7
  const int lane = tid & 63;
  const int l16  = lane & 15;
  const int quad = lane >> 4;
  const int wm   = wave >> 2;         // 0..1
  const int wn   = wave & 3;          // 0..3

  const int nbx = N >> 7;             // 128-col tiles
  const int nwg = nbx * (M >> 8);
  int bid = blockIdx.x;
  if ((nwg & 7) == 0) bid = (bid & 7) * (nwg >> 3) + (bid >> 3);
  const int row0 = (bid / nbx) << 8;
  const int col0 = (bid % nbx) << 7;

  const int srow = lane >> 2;
  const int scol = (((lane & 3) ^ ((lane >> 3) & 3)) << 3);
  const unsigned short* ApL = A  + (size_t)(row0 + wave * 32 + srow) * K + scol;
  const unsigned short* BpL = Bt + (size_t)(col0 + wave * 16 + srow) * K + scol;

  unsigned short* ldsA = lds;             // buf*16384 + kh*8192 + row*32 + e
  unsigned short* ldsB = lds + 32768;     // buf*8192  + kh*4096 + row*32 + e
  const int wstA = wave * 1024;
  const int wstB = wave * 512;

  const int sl = ((quad ^ ((l16 >> 1) & 3)) << 3);
  const int arow = wm * 128 + l16;        // + i*16
  const int brow = wn * 32 + l16;         // + j*16

  f4v acc[8][2] = {};
  const int nt = K >> 6;

  // prologue: units in order Ak0(2), Bk0(1), Ak1(2), Bk1(1)
  gload16(ApL,                       ldsA + wstA);
  gload16(ApL + 16 * (size_t)K,      ldsA + wstA + 512);
  gload16(BpL,                       ldsB + wstB);
  gload16(ApL + 32,                  ldsA + 8192 + wstA);
  gload16(ApL + 32 + 16 * (size_t)K, ldsA + 8192 + wstA + 512);
  gload16(BpL + 32,                  ldsB + 4096 + wstB);
  asm volatile("s_waitcnt vmcnt(3)" ::: "memory");   // Ak0,Bk0 landed
  asm volatile("s_barrier" ::: "memory");

  for (int t = 0; t < nt; ++t) {
    const int p = t & 1;
    const unsigned short* Ab0 = ldsA + p * 16384;
    const unsigned short* Ab1 = Ab0 + 8192;
    const unsigned short* Bb0 = ldsB + p * 8192;
    const unsigned short* Bb1 = Bb0 + 4096;
    unsigned short* An = ldsA + (p ^ 1) * 16384;
    unsigned short* Bn = ldsB + (p ^ 1) * 8192;
    const bool pre = (t + 1 < nt);
    const unsigned short* sa = ApL + (size_t)(t + 1) * 64;
    const unsigned short* sb = BpL + (size_t)(t + 1) * 64;

    s8v a[8], b0, b1;

    // ---------- P0: k-half 0 ----------
    b0 = *(const s8v*)&Bb0[(brow +  0) * 32 + sl];
    b1 = *(const s8v*)&Bb0[(brow + 16) * 32 + sl];
#pragma unroll
    for (int i = 0; i < 8; ++i)
      a[i] = *(const s8v*)&Ab0[(arow + i * 16) * 32 + sl];
    if (pre) {
      gload16(sa,                  An + wstA);           // Ak0(t+1)
      gload16(sa + 16 * (size_t)K, An + wstA + 512);
      gload16(sb,                  Bn + wstB);           // Bk0(t+1)
    }
    __builtin_amdgcn_s_setprio(1);
#pragma unroll
    for (int i = 0; i < 8; ++i) {
      acc[i][0] = __builtin_amdgcn_mfma_f32_16x16x32_bf16(a[i], b0, acc[i][0], 0, 0, 0);
      acc[i][1] = __builtin_amdgcn_mfma_f32_16x16x32_bf16(a[i], b1, acc[i][1], 0, 0, 0);
    }
    __builtin_amdgcn_s_setprio(0);
    if (pre) { asm volatile("s_waitcnt vmcnt(3)" ::: "memory"); }  // Ak1,Bk1(t)
    else     { asm volatile("s_waitcnt vmcnt(0)" ::: "memory"); }
    asm volatile("s_barrier" ::: "memory");

    // ---------- P1: k-half 1 ----------
    b0 = *(const s8v*)&Bb1[(brow +  0) * 32 + sl];
    b1 = *(const s8v*)&Bb1[(brow + 16) * 32 + sl];
#pragma unroll
    for (int i = 0; i < 8; ++i)
      a[i] = *(const s8v*)&Ab1[(arow + i * 16) * 32 + sl];
    if (pre) {
      gload16(sa + 32,                  An + 8192 + wstA);   // Ak1(t+1)
      gload16(sa + 32 + 16 * (size_t)K, An + 8192 + wstA + 512);
      gload16(sb + 32,                  Bn + 4096 + wstB);   // Bk1(t+1)
    }
    __builtin_amdgcn_s_setprio(1);
#pragma unroll
    for (int i = 0; i < 8; ++i) {
      acc[i][0] = __builtin_amdgcn_mfma_f32_16x16x32_bf16(a[i], b0, acc[i][0], 0, 0, 0);
      acc[i][1] = __builtin_amdgcn_mfma_f32_16x16x32_bf16(a[i], b1, acc[i][1], 0, 0, 0);
    }
    __builtin_amdgcn_s_setprio(0);
    if (pre) { asm volatile("s_waitcnt vmcnt(3)" ::: "memory"); }  // Ak0,Bk0(t+1)
    asm volatile("s_barrier" ::: "memory");
  }

  // ---- epilogue: bias + store (fp32) ----
#pragma unroll
  for (int j = 0; j < 2; ++j) {
    const int col = col0 + wn * 32 + j * 16 + l16;
    const float bc = bias[col];
#pragma unroll
    for (int i = 0; i < 8; ++i) {
      const int rowb = row0 + wm * 128 + i * 16 + quad * 4;
#pragma unroll
      for (int r = 0; r < 4; ++r)
        C[(size_t)(rowb + r) * N + col] = acc[i][j][r] + bc;
    }
  }
}

// ---------------------------------------------------------------------------
// RoPE tables: ct/st [T][64] fp32
// ---------------------------------------------------------------------------
__global__ void sincos_tab(const int* __restrict__ pos, float* __restrict__ ct,
                           float* __restrict__ st)
{
  const int t = blockIdx.x, d = threadIdx.x;    // d < 64
  float inv = powf(1.0e6f, -(float)d * (1.0f / 64.0f));
  float fr  = (float)pos[t] * inv;
  float s, c;
  sincosf(fr, &s, &c);
  ct[t * 64 + d] = c;
  st[t * 64 + d] = s;
}

// ---------------------------------------------------------------------------
// RoPE apply on qkv [T][6144]: one block per token, 320 threads (5 waves),
// thread = (head hh, 8-elem d-group). 16B vector loads/stores. q heads
// (hh<32) pre-scaled by SCALE*log2(e) for exp2-domain softmax.
// ---------------------------------------------------------------------------
__global__ __launch_bounds__(320) void rope_apply2(
    unsigned short* __restrict__ qkv,
    const float* __restrict__ ct, const float* __restrict__ st, int T)
{
  const int t   = blockIdx.x;
  const int tid = threadIdx.x;            // 0..319
  const int hh  = tid >> 3;               // 0..39
  const int d0  = (tid & 7) << 3;         // 0,8,..,56
  unsigned short* p = qkv + (size_t)t * NQKV_ + hh * HD_;
  const float g = (hh < H_) ? (0.08838834764831845f * 1.4426950408889634f) : 1.0f;

  s8v x1 = *(const s8v*)(p + d0);
  s8v x2 = *(const s8v*)(p + 64 + d0);
  const float4* cp = (const float4*)(ct + t * 64 + d0);
  const float4* sp = (const float4*)(st + t * 64 + d0);
  float4 ca = cp[0], cb = cp[1], sa = sp[0], sb = sp[1];
  float cc[8] = {ca.x, ca.y, ca.z, ca.w, cb.x, cb.y, cb.z, cb.w};
  float ss[8] = {sa.x, sa.y, sa.z, sa.w, sb.x, sb.y, sb.z, sb.w};

  s8v o1, o2;
#pragma unroll
  for (int u = 0; u < 8; ++u) {
    float a = b2f((unsigned short)x1[u]);
    float b = b2f((unsigned short)x2[u]);
    o1[u] = (short)f2b((a * cc[u] - b * ss[u]) * g);
    o2[u] = (short)f2b((b * cc[u] + a * ss[u]) * g);
  }
  *(s8v*)(p + d0)      = o1;
  *(s8v*)(p + 64 + d0) = o2;
}

// ---------------------------------------------------------------------------
// Block-sparse flash attention. Q rows in qkv (stride ldq, col h*128),
// K rows in qkv (stride ldq, col 4096 + hkv*128), Vt [KVD][T], O [T][4096].
// ---------------------------------------------------------------------------
__global__ __launch_bounds__(256) void attn_sparse(
    const unsigned short* __restrict__ QKV, int ldq,
    const unsigned short* __restrict__ Vt, unsigned short* __restrict__ O, int T)
{
  __shared__ __align__(16) unsigned short lds[16384];   // 32 KB
  unsigned short* ldsK = lds;            // Ks(s,key,c) = s*2048 + key*32 + c
  unsigned short* ldsV = lds + 8192;     // Vs(p,d,c)   = p*4096 + d*32 + c
  unsigned short* ldsP = lds;            // Ps alias (K dead after S-MFMAs)

  const int h    = blockIdx.x;
  const int qb   = (gridDim.y - 1) - blockIdx.y;   // heavy blocks first
  const int hkv  = h >> 2;
  const int tid  = threadIdx.x;
  const int wave = tid >> 6;
  const int lane = tid & 63;
  const int l16  = lane & 15;
  const int quad = lane >> 4;

  const int qrow = qb * 64 + wave * 16 + l16;
  s8v qf[4];
#pragma unroll
  for (int s = 0; s < 4; ++s)
    qf[s] = *(const s8v*)(QKV + (size_t)qrow * ldq + h * HD_ + s * 32 + quad * 8);

  const int lr4 = lane >> 2;
  const int lc8 = (lane & 3) << 3;
  const unsigned short* Kp0 = QKV + (size_t)(wave * 16 + lr4) * ldq
                              + D_ + hkv * HD_ + lc8;
  unsigned short* Kd0 = ldsK + wave * 512;
  const unsigned short* Vp0 = Vt + (size_t)(hkv * HD_ + wave * 32 + lr4) * T + lc8;
  unsigned short* Vd0 = ldsV + wave * 1024;

  float mrow[4] = {-1e30f, -1e30f, -1e30f, -1e30f};
  float lrow[4] = {0.f, 0.f, 0.f, 0.f};
  f4v oacc[8] = {};
  const int rowinb = wave * 16 + quad * 4;

  for (int kb = 0; kb <= qb; ++kb) {
    if (!((qb - kb < 16) || (((kb + h + 1) & 7) == 0))) continue;

    __syncthreads();                     // prior PV reads done
    {
      const unsigned short* kp = Kp0 + (size_t)(kb * 64) * ldq;
      const unsigned short* vp = Vp0 + kb * 64;
#pragma unroll
      for (int t = 0; t < 4; ++t)
        gload16(kp + t * 32, Kd0 + t * 2048);
#pragma unroll
      for (int t = 0; t < 4; ++t)
        gload16(vp + (size_t)((t >> 1) * 16) * T + (t & 1) * 32,
                Vd0 + (t & 1) * 4096 + (t >> 1) * 512);
    }
    __syncthreads();                     // staging visible

    f4v sacc[4] = {};
#pragma unroll
    for (int kt = 0; kt < 4; ++kt) {
#pragma unroll
      for (int s = 0; s < 4; ++s) {
        s8v b = *(const s8v*)&ldsK[s * 2048 + (kt * 16 + l16) * 32 + quad * 8];
        sacc[kt] = __builtin_amdgcn_mfma_f32_16x16x32_bf16(qf[s], b, sacc[kt], 0, 0, 0);
      }
    }
    __syncthreads();                     // all waves done reading Ks

    const bool diag = (kb == qb);
    float p[4][4];
#pragma unroll
    for (int r = 0; r < 4; ++r) {
      float mx = -1e30f;
#pragma unroll
      for (int kt = 0; kt < 4; ++kt) {
        float sc = sacc[kt][r];
        if (diag && (kt * 16 + l16 > rowinb + r)) sc = -1e30f;
        p[r][kt] = sc;
        mx = fmaxf(mx, sc);
      }
#pragma unroll
      for (int off = 1; off < 16; off <<= 1)
        mx = fmaxf(mx, __shfl_xor(mx, off));
      float newm = fmaxf(mrow[r], mx);
      float alpha = exp2f(mrow[r] - newm);
      mrow[r] = newm;
      float rs = 0.f;
#pragma unroll
      for (int kt = 0; kt < 4; ++kt) {
        unsigned short pb = f2b(exp2f(p[r][kt] - newm));
        ldsP[wave * 1152 + (quad * 4 + r) * 72 + kt * 16 + l16] = pb;
        rs += b2f(pb);
      }
#pragma unroll
      for (int off = 1; off < 16; off <<= 1)
        rs += __shfl_xor(rs, off);
      lrow[r] = lrow[r] * alpha + rs;
#pragma unroll
      for (int dt = 0; dt < 8; ++dt) oacc[dt][r] *= alpha;
    }

#pragma unroll
    for (int s2 = 0; s2 < 2; ++s2) {
      s8v af = *(const s8v*)&ldsP[wave * 1152 + l16 * 72 + s2 * 32 + quad * 8];
#pragma unroll
      for (int dt = 0; dt < 8; ++dt) {
        s8v vf = *(const s8v*)&ldsV[s2 * 4096 + (dt * 16 + l16) * 32 + quad * 8];
        oacc[dt] = __builtin_amdgcn_mfma_f32_16x16x32_bf16(af, vf, oacc[dt], 0, 0, 0);
      }
    }
  }

#pragma unroll
  for (int r = 0; r < 4; ++r) {
    float inv = 1.0f / lrow[r];
    size_t rowoff = (size_t)(qb * 64 + rowinb + r) * D_ + h * HD_;
#pragma unroll
    for (int dt = 0; dt < 8; ++dt)
      O[rowoff + dt * 16 + l16] = f2b(oacc[dt][r] * inv);
  }
}

// ---------------------------------------------------------------------------
extern "C" void kernel_launch(void* const* d_in, const int* in_sizes, int n_in,
                              void* d_out, int out_size, void* d_ws, size_t ws_size,
                              hipStream_t stream)
{
  const float* hs  = (const float*)d_in[0];
  const int*   pos = (const int*)d_in[1];
  const float* Wq  = (const float*)d_in[2];
  const float* bq  = (const float*)d_in[3];
  const float* Wk  = (const float*)d_in[4];
  const float* bk  = (const float*)d_in[5];
  const float* Wv  = (const float*)d_in[6];
  const float* bv  = (const float*)d_in[7];
  const float* Wo  = (const float*)d_in[8];
  const float* bo  = (const float*)d_in[9];
  float* out = (float*)d_out;

  const int T = in_sizes[1];   // 2048

  // workspace layout (ushort elems), ~97.5 MB total:
  //  hsb [T*4096]     (aliases attn output abuf after QKV gemm)
  //  qkv [T*6144]
  //  vt  [1024*T]
  //  wbuf[6144*4096]  (WqkvT; later WoT)
  //  bqkv fp32[6144] | ct fp32[T*64] | st fp32[T*64]
  const size_t nQ = (size_t)T * D_;
  unsigned short* hsb  = (unsigned short*)d_ws;
  unsigned short* qkv  = hsb + nQ;
  unsigned short* vt   = qkv + (size_t)T * NQKV_;
  unsigned short* wbuf = vt  + (size_t)KVD_ * T;
  unsigned short* tail = wbuf + (size_t)NQKV_ * D_;
  float* bqkv = (float*)tail;
  float* ct   = bqkv + NQKV_;
  float* st   = ct + (size_t)T * 64;
  unsigned short* abuf = hsb;   // alias: attn output, read by O-proj

  dim3 blk(256);
  cvt_bf16<<<dim3((int)(nQ / 8 / 256)), blk, 0, stream>>>(hs, hsb, (int)(nQ / 8));
  concat_bias<<<dim3(NQKV_ / 256), blk, 0, stream>>>(bq, bk, bv, bqkv);
  sincos_tab<<<dim3(T), dim3(64), 0, stream>>>(pos, ct, st);

  // WqkvT: rows 0..4095 = WqT, 4096..5119 = WkT, 5120..6143 = WvT
  cvt_transpose<<<dim3(D_ / 64,   D_ / 64), blk, 0, stream>>>(Wq, wbuf, D_, D_);
  cvt_transpose<<<dim3(KVD_ / 64, D_ / 64), blk, 0, stream>>>(
      Wk, wbuf + (size_t)D_ * D_, D_, KVD_);
  cvt_transpose<<<dim3(KVD_ / 64, D_ / 64), blk, 0, stream>>>(
      Wv, wbuf + (size_t)(D_ + KVD_) * D_, D_, KVD_);

  // fused QKV projection: qkv[T][6144] (256^2 tile, 4-wave 128x128 wave-tile)
  gemm_w128<<<dim3((NQKV_ / 256) * (T / 256)), dim3(256), 0, stream>>>(
      hsb, wbuf, bqkv, qkv, T, NQKV_, D_, NQKV_);

  rope_apply2<<<dim3(T), dim3(320), 0, stream>>>(qkv, ct, st, T);
  vtrans<<<dim3(KVD_ / 64, T / 64), blk, 0, stream>>>(
      qkv + D_ + KVD_, NQKV_, vt, T);

  attn_sparse<<<dim3(H_, T / 64), blk, 0, stream>>>(qkv, NQKV_, vt, abuf, T);

  // O-proj: 256x128-tile 2-phase GEMM, 256 wgs exact full coverage
  cvt_transpose<<<dim3(D_ / 64, D_ / 64), blk, 0, stream>>>(Wo, wbuf, D_, D_);
  gemm_on<<<dim3((D_ / 128) * (T / 256)), dim3(512), 0, stream>>>(
      abuf, wbuf, bo, out, T, D_, D_);
}

// Round 9
// 491.846 us; speedup vs baseline: 1.1074x; 1.1074x over previous
//
#include <hip/hip_runtime.h>
#include <type_traits>

#define H_    32
#define HKV_  8
#define HD_   128
#define D_    4096   // H*HD
#define KVD_  1024   // HKV*HD
#define NQKV_ 6144   // D_ + 2*KVD_

typedef __attribute__((ext_vector_type(8))) short s8v;   // 8 x bf16 bits (4 VGPRs)
typedef __attribute__((ext_vector_type(4))) float f4v;

__device__ __forceinline__ float b2f(unsigned short u) {
  union { unsigned int i; float f; } v; v.i = ((unsigned int)u) << 16; return v.f;
}
__device__ __forceinline__ unsigned short f2b(float f) {
  unsigned int u = __float_as_uint(f);
  u += 0x7fffu + ((u >> 16) & 1u);          // round-to-nearest-even
  return (unsigned short)(u >> 16);
}

// async global->LDS, 16B/lane; LDS dest = wave-uniform base, HW adds lane*16
__device__ __forceinline__ void gload16(const unsigned short* g, unsigned short* l) {
  __builtin_amdgcn_global_load_lds((const __attribute__((address_space(1))) void*)g,
                                   (__attribute__((address_space(3))) void*)l, 16, 0, 0);
}

// ---------------------------------------------------------------------------
// fp32 -> bf16 flat convert (8 elems/thread)
// ---------------------------------------------------------------------------
__global__ void cvt_bf16(const float* __restrict__ x, unsigned short* __restrict__ y,
                         int n8)
{
  int i = blockIdx.x * blockDim.x + threadIdx.x;
  if (i >= n8) return;
  const float4* xp = (const float4*)x + (size_t)i * 2;
  float4 a = xp[0], b = xp[1];
  s8v v;
  v[0] = (short)f2b(a.x); v[1] = (short)f2b(a.y);
  v[2] = (short)f2b(a.z); v[3] = (short)f2b(a.w);
  v[4] = (short)f2b(b.x); v[5] = (short)f2b(b.y);
  v[6] = (short)f2b(b.z); v[7] = (short)f2b(b.w);
  *(s8v*)(y + (size_t)i * 8) = v;
}

// ---------------------------------------------------------------------------
// concat bq|bk|bv -> bqkv fp32 [6144]
// ---------------------------------------------------------------------------
__global__ void concat_bias(const float* __restrict__ bq, const float* __restrict__ bk,
                            const float* __restrict__ bv, float* __restrict__ o)
{
  int i = blockIdx.x * blockDim.x + threadIdx.x;   // < 6144
  float v = (i < D_) ? bq[i] : (i < D_ + KVD_) ? bk[i - D_] : bv[i - D_ - KVD_];
  o[i] = v;
}

// ---------------------------------------------------------------------------
// W [K][N] fp32 -> Wt [N][K] bf16, 64x64 LDS-tiled transpose+convert
// ---------------------------------------------------------------------------
__global__ __launch_bounds__(256) void cvt_transpose(
    const float* __restrict__ W, unsigned short* __restrict__ Wt, int K, int N)
{
  __shared__ unsigned short tile[64][72];
  const int k0 = blockIdx.y * 64, n0 = blockIdx.x * 64;
  const int tid = threadIdx.x;
#pragma unroll
  for (int it = 0; it < 4; ++it) {
    int idx = tid + it * 256;
    int r = idx >> 4;
    int c = (idx & 15) << 2;
    float4 w = *(const float4*)(W + (size_t)(k0 + r) * N + n0 + c);
    tile[c + 0][r] = f2b(w.x); tile[c + 1][r] = f2b(w.y);
    tile[c + 2][r] = f2b(w.z); tile[c + 3][r] = f2b(w.w);
  }
  __syncthreads();
#pragma unroll
  for (int it = 0; it < 2; ++it) {
    int idx = tid + it * 256;
    int n = idx >> 3;
    int kk = (idx & 7) << 3;
    *(s8v*)(Wt + (size_t)(n0 + n) * K + k0 + kk) = *(const s8v*)&tile[n][kk];
  }
}

// ---------------------------------------------------------------------------
// bf16 [T][*] column-slice -> transposed [n][T]. Src stride lds_, 64x64 tiles.
// ---------------------------------------------------------------------------
__global__ __launch_bounds__(256) void vtrans(
    const unsigned short* __restrict__ S, int lds_, unsigned short* __restrict__ Dst,
    int T)
{
  __shared__ unsigned short tile[64][72];
  const int v0 = blockIdx.x * 64, t0 = blockIdx.y * 64;
  const int tid = threadIdx.x;
#pragma unroll
  for (int it = 0; it < 2; ++it) {
    int idx = tid + it * 256;           // 0..511
    int tr = idx >> 3;                  // 0..63
    int vc = (idx & 7) << 3;            // 0..56
    s8v val = *(const s8v*)(S + (size_t)(t0 + tr) * lds_ + v0 + vc);
#pragma unroll
    for (int u = 0; u < 8; ++u) tile[vc + u][tr] = (unsigned short)val[u];
  }
  __syncthreads();
#pragma unroll
  for (int it = 0; it < 2; ++it) {
    int idx = tid + it * 256;
    int vr = idx >> 3;
    int tc = (idx & 7) << 3;
    *(s8v*)(Dst + (size_t)(v0 + vr) * T + t0 + tc) = *(const s8v*)&tile[vr][tc];
  }
}

// ---------------------------------------------------------------------------
// 256x256-tile 4-phase pipelined GEMM: C[M][N](ldc) = A[M][K] @ Bt[N][K]^T + b
// BK=64, 8 waves (2Mx4N, wave-tile 128x64), 512 threads, 2-deep LDS dbuf.
// LDS [buf][khalf][256 rows][32 elems]; 16B-slot sigma-swizzle:
//   phys slot s of row r holds logical chunk s ^ ((r>>1)&3)
// -> frag ds_read_b128 conflict-free; both sides lane-constant.
// Schedule per K-tile: 2 barriers + 2 counted vmcnt(4), never 0 in-loop.
// Requires M%256==0, N%256==0, K%64==0, K/64>=2.
// ---------------------------------------------------------------------------
template <typename OT>
__global__ __launch_bounds__(512, 2) void gemm_bt4p(
    const unsigned short* __restrict__ A, const unsigned short* __restrict__ Bt,
    const float* __restrict__ bias, OT* __restrict__ C,
    int M, int N, int K, int ldc)
{
  __shared__ __align__(16) unsigned short lds[65536];   // 128 KiB

  const int tid  = threadIdx.x;
  const int wave = tid >> 6;          // 0..7
  const int lane = tid & 63;
  const int l16  = lane & 15;
  const int quad = lane >> 4;
  const int wm   = wave >> 2;         // 0..1
  const int wn   = wave & 3;          // 0..3

  // XCD-bijective chunk swizzle (each XCD gets contiguous tiles = shared A)
  const int nbx = N >> 8;
  const int nwg = nbx * (M >> 8);
  int bid = blockIdx.x;
  if ((nwg & 7) == 0) bid = (bid & 7) * (nwg >> 3) + (bid >> 3);
  const int row0 = (bid / nbx) << 8;
  const int col0 = (bid % nbx) << 8;

  // staging source: lane covers row w*32 + c*16 + (lane>>2); its 16B chunk is
  // sigma-permuted: chunk = (lane&3) ^ ((lane>>3)&3)  (lane-constant)
  const int srow = lane >> 2;
  const int scol = (((lane & 3) ^ ((lane >> 3) & 3)) << 3);
  const unsigned short* ApL = A  + (size_t)(row0 + wave * 32 + srow) * K + scol;
  const unsigned short* BpL = Bt + (size_t)(col0 + wave * 32 + srow) * K + scol;

  unsigned short* ldsA = lds;             // p*16384 + kh*8192 + row*32 + e
  unsigned short* ldsB = lds + 32768;
  const int wst = wave * 1024;            // per-wave offset inside a kh-plane

  // frag-read slot addend (lane-constant): quad ^ ((l16>>1)&3)
  const int sl = ((quad ^ ((l16 >> 1) & 3)) << 3);
  const int arow = wm * 128 + l16;        // + i*16
  const int brow = wn * 64 + l16;         // + j*16

  f4v acc[8][4] = {};
  const int nt = K >> 6;

  // prologue: stage tile 0 (units Ak0,Bk0,Ak1,Bk1 = 8 loads)
  {
    const unsigned short* sa = ApL;
    const unsigned short* sb = BpL;
    gload16(sa,                       ldsA + wst);
    gload16(sa + 16 * (size_t)K,      ldsA + wst + 512);
    gload16(sb,                       ldsB + wst);
    gload16(sb + 16 * (size_t)K,      ldsB + wst + 512);
    gload16(sa + 32,                  ldsA + 8192 + wst);
    gload16(sa + 32 + 16 * (size_t)K, ldsA + 8192 + wst + 512);
    gload16(sb + 32,                  ldsB + 8192 + wst);
    gload16(sb + 32 + 16 * (size_t)K, ldsB + 8192 + wst + 512);
  }
  asm volatile("s_waitcnt vmcnt(4)" ::: "memory");   // Ak0(0),Bk0(0) landed
  asm volatile("s_barrier" ::: "memory");

  for (int t = 0; t < nt; ++t) {
    const int p = t & 1;
    const unsigned short* Ab0 = ldsA + p * 16384;        // k-half 0
    const unsigned short* Ab1 = Ab0 + 8192;              // k-half 1
    const unsigned short* Bb0 = ldsB + p * 16384;
    const unsigned short* Bb1 = Bb0 + 8192;
    unsigned short* An = ldsA + (p ^ 1) * 16384;
    unsigned short* Bn = ldsB + (p ^ 1) * 16384;
    const bool pre = (t + 1 < nt);
    const unsigned short* sa = ApL + (size_t)(t + 1) * 64;
    const unsigned short* sb = BpL + (size_t)(t + 1) * 64;

    s8v a[8], b0, b1, b2, b3;

    // ---------- P0: k0, n j01 ----------
    b0 = *(const s8v*)&Bb0[(brow +  0) * 32 + sl];
    b1 = *(const s8v*)&Bb0[(brow + 16) * 32 + sl];
#pragma unroll
    for (int i = 0; i < 8; ++i)
      a[i] = *(const s8v*)&Ab0[(arow + i * 16) * 32 + sl];
    if (pre) {
      gload16(sa,                  An + wst);            // Ak0(t+1)
      gload16(sa + 16 * (size_t)K, An + wst + 512);
    }
    __builtin_amdgcn_s_setprio(1);
#pragma unroll
    for (int i = 0; i < 8; ++i) {
      acc[i][0] = __builtin_amdgcn_mfma_f32_16x16x32_bf16(a[i], b0, acc[i][0], 0, 0, 0);
      acc[i][1] = __builtin_amdgcn_mfma_f32_16x16x32_bf16(a[i], b1, acc[i][1], 0, 0, 0);
    }
    __builtin_amdgcn_s_setprio(0);

    // ---------- P1: k0, n j23 ----------
    b2 = *(const s8v*)&Bb0[(brow + 32) * 32 + sl];
    b3 = *(const s8v*)&Bb0[(brow + 48) * 32 + sl];
    if (pre) {
      gload16(sb,                  Bn + wst);            // Bk0(t+1)
      gload16(sb + 16 * (size_t)K, Bn + wst + 512);
      asm volatile("s_waitcnt vmcnt(4)" ::: "memory");   // Ak1(t),Bk1(t) landed
    } else {
      asm volatile("s_waitcnt vmcnt(0)" ::: "memory");
    }
    asm volatile("s_barrier" ::: "memory");
    __builtin_amdgcn_s_setprio(1);
#pragma unroll
    for (int i = 0; i < 8; ++i) {
      acc[i][2] = __builtin_amdgcn_mfma_f32_16x16x32_bf16(a[i], b2, acc[i][2], 0, 0, 0);
      acc[i][3] = __builtin_amdgcn_mfma_f32_16x16x32_bf16(a[i], b3, acc[i][3], 0, 0, 0);
    }
    __builtin_amdgcn_s_setprio(0);

    // ---------- P2: k1, n j23 ----------
    b2 = *(const s8v*)&Bb1[(brow + 32) * 32 + sl];
    b3 = *(const s8v*)&Bb1[(brow + 48) * 32 + sl];
#pragma unroll
    for (int i = 0; i < 8; ++i)
      a[i] = *(const s8v*)&Ab1[(arow + i * 16) * 32 + sl];
    if (pre) {
      gload16(sa + 32,                  An + 8192 + wst);   // Ak1(t+1)
      gload16(sa + 32 + 16 * (size_t)K, An + 8192 + wst + 512);
    }
    __builtin_amdgcn_s_setprio(1);
#pragma unroll
    for (int i = 0; i < 8; ++i) {
      acc[i][2] = __builtin_amdgcn_mfma_f32_16x16x32_bf16(a[i], b2, acc[i][2], 0, 0, 0);
      acc[i][3] = __builtin_amdgcn_mfma_f32_16x16x32_bf16(a[i], b3, acc[i][3], 0, 0, 0);
    }
    __builtin_amdgcn_s_setprio(0);

    // ---------- P3: k1, n j01 ----------
    b0 = *(const s8v*)&Bb1[(brow +  0) * 32 + sl];
    b1 = *(const s8v*)&Bb1[(brow + 16) * 32 + sl];
    if (pre) {
      gload16(sb + 32,                  Bn + 8192 + wst);   // Bk1(t+1)
      gload16(sb + 32 + 16 * (size_t)K, Bn + 8192 + wst + 512);
      asm volatile("s_waitcnt vmcnt(4)" ::: "memory");   // Ak0,Bk0(t+1) landed
    }
    asm volatile("s_barrier" ::: "memory");
    __builtin_amdgcn_s_setprio(1);
#pragma unroll
    for (int i = 0; i < 8; ++i) {
      acc[i][0] = __builtin_amdgcn_mfma_f32_16x16x32_bf16(a[i], b0, acc[i][0], 0, 0, 0);
      acc[i][1] = __builtin_amdgcn_mfma_f32_16x16x32_bf16(a[i], b1, acc[i][1], 0, 0, 0);
    }
    __builtin_amdgcn_s_setprio(0);
  }

  // ---- epilogue: bias + store ----
#pragma unroll
  for (int j = 0; j < 4; ++j) {
    const int col = col0 + wn * 64 + j * 16 + l16;
    const float bc = bias[col];
#pragma unroll
    for (int i = 0; i < 8; ++i) {
      const int rowb = row0 + wm * 128 + i * 16 + quad * 4;
#pragma unroll
      for (int r = 0; r < 4; ++r) {
        float o = acc[i][j][r] + bc;
        if constexpr (std::is_same_v<OT, float>) C[(size_t)(rowb + r) * ldc + col] = o;
        else                                     C[(size_t)(rowb + r) * ldc + col] = f2b(o);
      }
    }
  }
}

// ---------------------------------------------------------------------------
// 128x256-tile 2-phase pipelined GEMM (O-proj): full 256-wg coverage at 1/CU
// with the best feasible wave-tile geometry (8 waves of 64x64; frag LDS
// traffic 128KB/K-tile vs gemm_on's 160KB at 128x32 wave-tiles):
//   C[M][N] fp32 = A[M][K] @ Bt[N][K]^T + bias
// BK=64, 512 threads (2Mx4N waves), 2-deep dbuf, LDS 96 KiB (A 32K + B 64K).
// Same sigma-swizzle; A/B-mirrored gemm_on ledger: units per k-half are
// {A 1 load, B 2 loads} = 3 loads/phase. Prologue 6 loads + vmcnt(3)
// [Ak0,Bk0 landed]; P0 issues {Ak0,Bk0}(t+1) then vmcnt(3) retires
// {Ak1,Bk1}(t); P1 issues {Ak1,Bk1}(t+1) then vmcnt(3) retires
// {Ak0,Bk0}(t+1). vmcnt(0) only in tail.
// Requires M%128==0, N%256==0, K%64==0, K/64>=2.
// ---------------------------------------------------------------------------
__global__ __launch_bounds__(512, 1) void gemm_o2(
    const unsigned short* __restrict__ A, const unsigned short* __restrict__ Bt,
    const float* __restrict__ bias, float* __restrict__ C,
    int M, int N, int K)
{
  __shared__ __align__(16) unsigned short lds[49152];   // 96 KiB

  const int tid  = threadIdx.x;
  const int wave = tid >> 6;          // 0..7
  const int lane = tid & 63;
  const int l16  = lane & 15;
  const int quad = lane >> 4;
  const int wm   = wave >> 2;         // 0..1  (64-row half)
  const int wn   = wave & 3;          // 0..3  (64-col quarter)

  const int nbx = N >> 8;             // 256-col tiles
  const int nwg = nbx * (M >> 7);
  int bid = blockIdx.x;
  if ((nwg & 7) == 0) bid = (bid & 7) * (nwg >> 3) + (bid >> 3);
  const int row0 = (bid / nbx) << 7;
  const int col0 = (bid % nbx) << 8;

  // staging: A-half = 128 rows x 32 elems = 8KB = 1 load/thread (wave covers
  // 16 rows); B-half = 256 rows = 2 loads/thread (rows +0/+16, wave covers 32)
  const int srow = lane >> 2;
  const int scol = (((lane & 3) ^ ((lane >> 3) & 3)) << 3);
  const unsigned short* ApL = A  + (size_t)(row0 + wave * 16 + srow) * K + scol;
  const unsigned short* BpL = Bt + (size_t)(col0 + wave * 32 + srow) * K + scol;

  unsigned short* ldsA = lds;             // buf*8192  + kh*4096 + row*32 + e
  unsigned short* ldsB = lds + 16384;     // buf*16384 + kh*8192 + row*32 + e
  const int wstA = wave * 512;            // 16 rows * 32 elems
  const int wstB = wave * 1024;           // 32 rows * 32 elems

  const int sl = ((quad ^ ((l16 >> 1) & 3)) << 3);
  const int arow = wm * 64 + l16;         // + i*16
  const int brow = wn * 64 + l16;         // + j*16

  f4v acc[4][4] = {};
  const int nt = K >> 6;

  // prologue: units {Ak0(1),Bk0(2)}, {Ak1(1),Bk1(2)} = 6 loads
  gload16(ApL,                       ldsA + wstA);
  gload16(BpL,                       ldsB + wstB);
  gload16(BpL + 16 * (size_t)K,      ldsB + wstB + 512);
  gload16(ApL + 32,                  ldsA + 4096 + wstA);
  gload16(BpL + 32,                  ldsB + 8192 + wstB);
  gload16(BpL + 32 + 16 * (size_t)K, ldsB + 8192 + wstB + 512);
  asm volatile("s_waitcnt vmcnt(3)" ::: "memory");   // Ak0,Bk0 landed
  asm volatile("s_barrier" ::: "memory");

  for (int t = 0; t < nt; ++t) {
    const int p = t & 1;
    const unsigned short* Ab0 = ldsA + p * 8192;       // k-half 0
    const unsigned short* Ab1 = Ab0 + 4096;            // k-half 1
    const unsigned short* Bb0 = ldsB + p * 16384;
    const unsigned short* Bb1 = Bb0 + 8192;
    unsigned short* An = ldsA + (p ^ 1) * 8192;
    unsigned short* Bn = ldsB + (p ^ 1) * 16384;
    const bool pre = (t + 1 < nt);
    const unsigned short* sa = ApL + (size_t)(t + 1) * 64;
    const unsigned short* sb = BpL + (size_t)(t + 1) * 64;

    s8v a[4], b[4];

    // ---------- P0: k-half 0 ----------
#pragma unroll
    for (int i = 0; i < 4; ++i)
      a[i] = *(const s8v*)&Ab0[(arow + i * 16) * 32 + sl];
#pragma unroll
    for (int j = 0; j < 4; ++j)
      b[j] = *(const s8v*)&Bb0[(brow + j * 16) * 32 + sl];
    if (pre) {
      gload16(sa,                  An + wstA);         // Ak0(t+1)
      gload16(sb,                  Bn + wstB);         // Bk0(t+1)
      gload16(sb + 16 * (size_t)K, Bn + wstB + 512);
    }
    __builtin_amdgcn_s_setprio(1);
#pragma unroll
    for (int i = 0; i < 4; ++i)
#pragma unroll
      for (int j = 0; j < 4; ++j)
        acc[i][j] = __builtin_amdgcn_mfma_f32_16x16x32_bf16(a[i], b[j], acc[i][j], 0, 0, 0);
    __builtin_amdgcn_s_setprio(0);
    if (pre) { asm volatile("s_waitcnt vmcnt(3)" ::: "memory"); }  // Ak1,Bk1(t)
    else     { asm volatile("s_waitcnt vmcnt(0)" ::: "memory"); }
    asm volatile("s_barrier" ::: "memory");

    // ---------- P1: k-half 1 ----------
#pragma unroll
    for (int i = 0; i < 4; ++i)
      a[i] = *(const s8v*)&Ab1[(arow + i * 16) * 32 + sl];
#pragma unroll
    for (int j = 0; j < 4; ++j)
      b[j] = *(const s8v*)&Bb1[(brow + j * 16) * 32 + sl];
    if (pre) {
      gload16(sa + 32,                  An + 4096 + wstA);   // Ak1(t+1)
      gload16(sb + 32,                  Bn + 8192 + wstB);   // Bk1(t+1)
      gload16(sb + 32 + 16 * (size_t)K, Bn + 8192 + wstB + 512);
    }
    __builtin_amdgcn_s_setprio(1);
#pragma unroll
    for (int i = 0; i < 4; ++i)
#pragma unroll
      for (int j = 0; j < 4; ++j)
        acc[i][j] = __builtin_amdgcn_mfma_f32_16x16x32_bf16(a[i], b[j], acc[i][j], 0, 0, 0);
    __builtin_amdgcn_s_setprio(0);
    if (pre) { asm volatile("s_waitcnt vmcnt(3)" ::: "memory"); }  // Ak0,Bk0(t+1)
    asm volatile("s_barrier" ::: "memory");
  }

  // ---- epilogue: bias + store (fp32) ----
#pragma unroll
  for (int j = 0; j < 4; ++j) {
    const int col = col0 + wn * 64 + j * 16 + l16;
    const float bc = bias[col];
#pragma unroll
    for (int i = 0; i < 4; ++i) {
      const int rowb = row0 + wm * 64 + i * 16 + quad * 4;
#pragma unroll
      for (int r = 0; r < 4; ++r)
        C[(size_t)(rowb + r) * N + col] = acc[i][j][r] + bc;
    }
  }
}

// ---------------------------------------------------------------------------
// RoPE tables: ct/st [T][64] fp32
// ---------------------------------------------------------------------------
__global__ void sincos_tab(const int* __restrict__ pos, float* __restrict__ ct,
                           float* __restrict__ st)
{
  const int t = blockIdx.x, d = threadIdx.x;    // d < 64
  float inv = powf(1.0e6f, -(float)d * (1.0f / 64.0f));
  float fr  = (float)pos[t] * inv;
  float s, c;
  sincosf(fr, &s, &c);
  ct[t * 64 + d] = c;
  st[t * 64 + d] = s;
}

// ---------------------------------------------------------------------------
// RoPE apply on qkv [T][6144]: one block per token, 320 threads (5 waves),
// thread = (head hh, 8-elem d-group). 16B vector loads/stores. q heads
// (hh<32) pre-scaled by SCALE*log2(e) for exp2-domain softmax.
// ---------------------------------------------------------------------------
__global__ __launch_bounds__(320) void rope_apply2(
    unsigned short* __restrict__ qkv,
    const float* __restrict__ ct, const float* __restrict__ st, int T)
{
  const int t   = blockIdx.x;
  const int tid = threadIdx.x;            // 0..319
  const int hh  = tid >> 3;               // 0..39
  const int d0  = (tid & 7) << 3;         // 0,8,..,56
  unsigned short* p = qkv + (size_t)t * NQKV_ + hh * HD_;
  const float g = (hh < H_) ? (0.08838834764831845f * 1.4426950408889634f) : 1.0f;

  s8v x1 = *(const s8v*)(p + d0);
  s8v x2 = *(const s8v*)(p + 64 + d0);
  const float4* cp = (const float4*)(ct + t * 64 + d0);
  const float4* sp = (const float4*)(st + t * 64 + d0);
  float4 ca = cp[0], cb = cp[1], sa = sp[0], sb = sp[1];
  float cc[8] = {ca.x, ca.y, ca.z, ca.w, cb.x, cb.y, cb.z, cb.w};
  float ss[8] = {sa.x, sa.y, sa.z, sa.w, sb.x, sb.y, sb.z, sb.w};

  s8v o1, o2;
#pragma unroll
  for (int u = 0; u < 8; ++u) {
    float a = b2f((unsigned short)x1[u]);
    float b = b2f((unsigned short)x2[u]);
    o1[u] = (short)f2b((a * cc[u] - b * ss[u]) * g);
    o2[u] = (short)f2b((b * cc[u] + a * ss[u]) * g);
  }
  *(s8v*)(p + d0)      = o1;
  *(s8v*)(p + 64 + d0) = o2;
}

// ---------------------------------------------------------------------------
// Block-sparse flash attention. Q rows in qkv (stride ldq, col h*128),
// K rows in qkv (stride ldq, col 4096 + hkv*128), Vt [KVD][T], O [T][4096].
// ---------------------------------------------------------------------------
__global__ __launch_bounds__(256) void attn_sparse(
    const unsigned short* __restrict__ QKV, int ldq,
    const unsigned short* __restrict__ Vt, unsigned short* __restrict__ O, int T)
{
  __shared__ __align__(16) unsigned short lds[16384];   // 32 KB
  unsigned short* ldsK = lds;            // Ks(s,key,c) = s*2048 + key*32 + c
  unsigned short* ldsV = lds + 8192;     // Vs(p,d,c)   = p*4096 + d*32 + c
  unsigned short* ldsP = lds;            // Ps alias (K dead after S-MFMAs)

  const int h    = blockIdx.x;
  const int qb   = (gridDim.y - 1) - blockIdx.y;   // heavy blocks first
  const int hkv  = h >> 2;
  const int tid  = threadIdx.x;
  const int wave = tid >> 6;
  const int lane = tid & 63;
  const int l16  = lane & 15;
  const int quad = lane >> 4;

  const int qrow = qb * 64 + wave * 16 + l16;
  s8v qf[4];
#pragma unroll
  for (int s = 0; s < 4; ++s)
    qf[s] = *(const s8v*)(QKV + (size_t)qrow * ldq + h * HD_ + s * 32 + quad * 8);

  const int lr4 = lane >> 2;
  const int lc8 = (lane & 3) << 3;
  const unsigned short* Kp0 = QKV + (size_t)(wave * 16 + lr4) * ldq
                              + D_ + hkv * HD_ + lc8;
  unsigned short* Kd0 = ldsK + wave * 512;
  const unsigned short* Vp0 = Vt + (size_t)(hkv * HD_ + wave * 32 + lr4) * T + lc8;
  unsigned short* Vd0 = ldsV + wave * 1024;

  float mrow[4] = {-1e30f, -1e30f, -1e30f, -1e30f};
  float lrow[4] = {0.f, 0.f, 0.f, 0.f};
  f4v oacc[8] = {};
  const int rowinb = wave * 16 + quad * 4;

  for (int kb = 0; kb <= qb; ++kb) {
    if (!((qb - kb < 16) || (((kb + h + 1) & 7) == 0))) continue;

    __syncthreads();                     // prior PV reads done
    {
      const unsigned short* kp = Kp0 + (size_t)(kb * 64) * ldq;
      const unsigned short* vp = Vp0 + kb * 64;
#pragma unroll
      for (int t = 0; t < 4; ++t)
        gload16(kp + t * 32, Kd0 + t * 2048);
#pragma unroll
      for (int t = 0; t < 4; ++t)
        gload16(vp + (size_t)((t >> 1) * 16) * T + (t & 1) * 32,
                Vd0 + (t & 1) * 4096 + (t >> 1) * 512);
    }
    __syncthreads();                     // staging visible

    f4v sacc[4] = {};
#pragma unroll
    for (int kt = 0; kt < 4; ++kt) {
#pragma unroll
      for (int s = 0; s < 4; ++s) {
        s8v b = *(const s8v*)&ldsK[s * 2048 + (kt * 16 + l16) * 32 + quad * 8];
        sacc[kt] = __builtin_amdgcn_mfma_f32_16x16x32_bf16(qf[s], b, sacc[kt], 0, 0, 0);
      }
    }
    __syncthreads();                     // all waves done reading Ks

    const bool diag = (kb == qb);
    float p[4][4];
#pragma unroll
    for (int r = 0; r < 4; ++r) {
      float mx = -1e30f;
#pragma unroll
      for (int kt = 0; kt < 4; ++kt) {
        float sc = sacc[kt][r];
        if (diag && (kt * 16 + l16 > rowinb + r)) sc = -1e30f;
        p[r][kt] = sc;
        mx = fmaxf(mx, sc);
      }
#pragma unroll
      for (int off = 1; off < 16; off <<= 1)
        mx = fmaxf(mx, __shfl_xor(mx, off));
      float newm = fmaxf(mrow[r], mx);
      float alpha = exp2f(mrow[r] - newm);
      mrow[r] = newm;
      float rs = 0.f;
#pragma unroll
      for (int kt = 0; kt < 4; ++kt) {
        unsigned short pb = f2b(exp2f(p[r][kt] - newm));
        ldsP[wave * 1152 + (quad * 4 + r) * 72 + kt * 16 + l16] = pb;
        rs += b2f(pb);
      }
#pragma unroll
      for (int off = 1; off < 16; off <<= 1)
        rs += __shfl_xor(rs, off);
      lrow[r] = lrow[r] * alpha + rs;
#pragma unroll
      for (int dt = 0; dt < 8; ++dt) oacc[dt][r] *= alpha;
    }

#pragma unroll
    for (int s2 = 0; s2 < 2; ++s2) {
      s8v af = *(const s8v*)&ldsP[wave * 1152 + l16 * 72 + s2 * 32 + quad * 8];
#pragma unroll
      for (int dt = 0; dt < 8; ++dt) {
        s8v vf = *(const s8v*)&ldsV[s2 * 4096 + (dt * 16 + l16) * 32 + quad * 8];
        oacc[dt] = __builtin_amdgcn_mfma_f32_16x16x32_bf16(af, vf, oacc[dt], 0, 0, 0);
      }
    }
  }

#pragma unroll
  for (int r = 0; r < 4; ++r) {
    float inv = 1.0f / lrow[r];
    size_t rowoff = (size_t)(qb * 64 + rowinb + r) * D_ + h * HD_;
#pragma unroll
    for (int dt = 0; dt < 8; ++dt)
      O[rowoff + dt * 16 + l16] = f2b(oacc[dt][r] * inv);
  }
}

// ---------------------------------------------------------------------------
extern "C" void kernel_launch(void* const* d_in, const int* in_sizes, int n_in,
                              void* d_out, int out_size, void* d_ws, size_t ws_size,
                              hipStream_t stream)
{
  const float* hs  = (const float*)d_in[0];
  const int*   pos = (const int*)d_in[1];
  const float* Wq  = (const float*)d_in[2];
  const float* bq  = (const float*)d_in[3];
  const float* Wk  = (const float*)d_in[4];
  const float* bk  = (const float*)d_in[5];
  const float* Wv  = (const float*)d_in[6];
  const float* bv  = (const float*)d_in[7];
  const float* Wo  = (const float*)d_in[8];
  const float* bo  = (const float*)d_in[9];
  float* out = (float*)d_out;

  const int T = in_sizes[1];   // 2048

  // workspace layout (ushort elems), ~97.5 MB total:
  //  hsb [T*4096]     (aliases attn output abuf after QKV gemm)
  //  qkv [T*6144]
  //  vt  [1024*T]
  //  wbuf[6144*4096]  (WqkvT; later WoT)
  //  bqkv fp32[6144] | ct fp32[T*64] | st fp32[T*64]
  const size_t nQ = (size_t)T * D_;
  unsigned short* hsb  = (unsigned short*)d_ws;
  unsigned short* qkv  = hsb + nQ;
  unsigned short* vt   = qkv + (size_t)T * NQKV_;
  unsigned short* wbuf = vt  + (size_t)KVD_ * T;
  unsigned short* tail = wbuf + (size_t)NQKV_ * D_;
  float* bqkv = (float*)tail;
  float* ct   = bqkv + NQKV_;
  float* st   = ct + (size_t)T * 64;
  unsigned short* abuf = hsb;   // alias: attn output, read by O-proj

  dim3 blk(256);
  cvt_bf16<<<dim3((int)(nQ / 8 / 256)), blk, 0, stream>>>(hs, hsb, (int)(nQ / 8));
  concat_bias<<<dim3(NQKV_ / 256), blk, 0, stream>>>(bq, bk, bv, bqkv);
  sincos_tab<<<dim3(T), dim3(64), 0, stream>>>(pos, ct, st);

  // WqkvT: rows 0..4095 = WqT, 4096..5119 = WkT, 5120..6143 = WvT
  cvt_transpose<<<dim3(D_ / 64,   D_ / 64), blk, 0, stream>>>(Wq, wbuf, D_, D_);
  cvt_transpose<<<dim3(KVD_ / 64, D_ / 64), blk, 0, stream>>>(
      Wk, wbuf + (size_t)D_ * D_, D_, KVD_);
  cvt_transpose<<<dim3(KVD_ / 64, D_ / 64), blk, 0, stream>>>(
      Wv, wbuf + (size_t)(D_ + KVD_) * D_, D_, KVD_);

  // fused QKV projection: qkv[T][6144]  (256^2 4-phase GEMM, 192 wgs)
  gemm_bt4p<unsigned short><<<dim3((NQKV_ / 256) * (T / 256)), dim3(512), 0, stream>>>(
      hsb, wbuf, bqkv, qkv, T, NQKV_, D_, NQKV_);

  rope_apply2<<<dim3(T), dim3(320), 0, stream>>>(qkv, ct, st, T);
  vtrans<<<dim3(KVD_ / 64, T / 64), blk, 0, stream>>>(
      qkv + D_ + KVD_, NQKV_, vt, T);

  attn_sparse<<<dim3(H_, T / 64), blk, 0, stream>>>(qkv, NQKV_, vt, abuf, T);

  // O-proj: 128x256-tile 2-phase GEMM, 256 wgs full coverage, 64x64 wave-tiles
  cvt_transpose<<<dim3(D_ / 64, D_ / 64), blk, 0, stream>>>(Wo, wbuf, D_, D_);
  gemm_o2<<<dim3((D_ / 256) * (T / 128)), dim3(512), 0, stream>>>(
      abuf, wbuf, bo, out, T, D_, D_);
}